// Round 4
// baseline (2440.481 us; speedup 1.0000x reference)
//
#include <hip/hip_runtime.h>
#include <hip/hip_bf16.h>

#define HH 512
#define FF 128
#define BB 2048
#define TT 96
#define NGATE 2048
#define NTOT 2176
#define GRP 32          // row groups (64 rows each)
#define CPB 16          // col-part blocks per group

typedef short short8 __attribute__((ext_vector_type(8)));
typedef float f32x4 __attribute__((ext_vector_type(4)));

union U128 { unsigned long long u[2]; short8 v; };

__device__ __forceinline__ float sigmoidf_(float x) { return 1.f / (1.f + __expf(-x)); }
__device__ __forceinline__ float tanhf_(float x) {
    float e = __expf(-2.f * fabsf(x));
    float t = (1.f - e) / (1.f + e);
    return x < 0.f ? -t : t;
}

// byte offset of element (m, k) in fragment order: 16(m) x 32(k) tiles of 1 KB,
// lane = (m&15) + 16*((k>>3)&3) holds bytes [lane*16, lane*16+16).
__device__ __forceinline__ size_t frag_off(int m, int k, int K) {
    return (size_t)((m >> 4) * (K >> 5) + (k >> 5)) * 1024
         + (size_t)(((k >> 3) & 3) * 256 + (m & 15) * 16 + (k & 7) * 2);
}

__device__ __forceinline__ short bf16bits(float f) {
    __hip_bfloat16 b = __float2bfloat16(f);
    return *(short*)&b;
}

// Gate col layout (n < 2048): octet o=n>>5, gate=(n>>3)&3, j=o*8+(n&7):
// each aligned 32-col group = [r(8) z(8) i_n(8) h_n(8)] for 8 consecutive j.
// Weights in B-fragment order. n>=2048: fc_w row -> Wfc.
__global__ __launch_bounds__(256) void build_weights(
    const float* __restrict__ w_ih, const float* __restrict__ w_hh,
    const float* __restrict__ b_ih, const float* __restrict__ b_hh,
    const float* __restrict__ fc_w, const float* __restrict__ fc_b,
    char* __restrict__ Wg, char* __restrict__ W0g, char* __restrict__ Wfc,
    float* __restrict__ bias, float* __restrict__ bias0)
{
    const int n = blockIdx.x;
    const int tid = threadIdx.x;
    __shared__ float wih_s[FF];
    const bool is_out = (n >= NGATE);
    int gate = 3, gidx = 0, f = 0;
    if (is_out) {
        f = n - NGATE;
    } else {
        int o = n >> 5;
        gate = (n >> 3) & 3;
        int j = o * 8 + (n & 7);
        gidx = (gate == 0) ? j : (gate == 1) ? (512 + j) : (1024 + j);
    }
    if (!is_out && gate != 3 && tid < FF) wih_s[tid] = w_ih[gidx * FF + tid];
    __syncthreads();

    for (int k = tid; k < HH; k += 256) {
        float w, w0;
        if (is_out) {
            w = fc_w[f * HH + k];
            w0 = 0.f;
        } else if (gate == 3) {
            w = w_hh[gidx * HH + k];
            w0 = w;
        } else {
            float comb = 0.f;
#pragma unroll 8
            for (int ff2 = 0; ff2 < FF; ++ff2) comb += wih_s[ff2] * fc_w[ff2 * HH + k];
            if (gate == 2) { w = comb; w0 = 0.f; }
            else { float whh = w_hh[gidx * HH + k]; w = whh + comb; w0 = whh; }
        }
        if (is_out) {
            *(short*)(Wfc + frag_off(f, k, HH)) = bf16bits(w);
        } else {
            *(short*)(Wg  + frag_off(n, k, HH)) = bf16bits(w);
            *(short*)(W0g + frag_off(n, k, HH)) = bf16bits(w0);
        }
    }
    if (tid == 0 && !is_out) {
        float b, b0;
        float cb = 0.f;
        if (gate != 3)
            for (int ff2 = 0; ff2 < FF; ++ff2) cb += fc_b[ff2] * w_ih[gidx * FF + ff2];
        if (gate <= 1)      { float s2 = b_ih[gidx] + b_hh[gidx]; b = s2 + cb; b0 = s2; }
        else if (gate == 2) { b = b_ih[gidx] + cb; b0 = b_ih[gidx]; }
        else                { b = b_hh[gidx]; b0 = b_hh[gidx]; }
        bias[n] = b; bias0[n] = b0;
    }
}

// hidden (fp32 row-major) -> h_0 bf16 in fragment order; zero sync counters.
__global__ __launch_bounds__(256) void init_misc(
    const float* __restrict__ hidden, char* __restrict__ hfrag, int* __restrict__ cnt)
{
    int i = blockIdx.x * 256 + threadIdx.x;  // 131072 granules of 8 k-elements
    int row = i >> 6, k0 = (i & 63) << 3;
    short8 v;
#pragma unroll
    for (int t = 0; t < 8; ++t) v[t] = bf16bits(hidden[(size_t)row * HH + k0 + t]);
    *(short8*)(hfrag + frag_off(row, k0, HH)) = v;
    if (i < GRP * 128) cnt[i] = 0;
}

#define GLD64(p) __hip_atomic_load((const unsigned long long*)(p), __ATOMIC_RELAXED, __HIP_MEMORY_SCOPE_AGENT)
#define GST64(p, v) __hip_atomic_store((unsigned long long*)(p), (v), __ATOMIC_RELAXED, __HIP_MEMORY_SCOPE_AGENT)

// Persistent GRU. 512 blocks = 32 row-groups(64 rows) x 16 col-parts(128 gate cols),
// 2 blocks/CU. Wave = 1 row-frag x 8 col-frags. A (h) streamed from L3 via relaxed
// agent atomics, rolling depth 8; B (weights) from L2 plain loads, depth 3.
// fc projection fused into the gate loop on blocks cp<8 (reuses A registers).
__global__ __launch_bounds__(256, 2) void gru_persist(
    const char* __restrict__ Wg, const char* __restrict__ W0g, const char* __restrict__ Wfc,
    const float* __restrict__ bias, const float* __restrict__ bias0,
    const float* __restrict__ fc_b, const float* __restrict__ hidden,
    char* __restrict__ hfrag0, char* __restrict__ hfrag1,
    float* __restrict__ out, int* __restrict__ cnt)
{
    __shared__ __align__(16) short hfr[4 * 512];   // 4 KB, fragment-ordered h_new

    const int tid = threadIdx.x;
    const int lane = tid & 63, w = tid >> 6;
    const int l15 = lane & 15, quad = lane >> 4;
    const int g = blockIdx.x & 31, cp = blockIdx.x >> 5;
    const int rf = g * 4 + w;                       // global row-frag of this wave

    const char* aB0 = hfrag0 + (size_t)rf * 16384 + lane * 16;
    const char* aB1 = hfrag1 + (size_t)rf * 16384 + lane * 16;
    const char* bb1 = Wg  + (size_t)(cp * 8) * 16384 + lane * 16;
    const char* bb0 = W0g + (size_t)(cp * 8) * 16384 + lane * 16;
    const char* bf  = Wfc + (size_t)cp * 16384 + lane * 16;   // valid for cp<8
    const bool fcblk = (cp < 8);

    float bv1[8];
#pragma unroll
    for (int ct = 0; ct < 8; ++ct) bv1[ct] = bias[cp * 128 + ct * 16 + l15];
    const float fcb = fcblk ? fc_b[cp * 16 + l15] : 0.f;

    // fp32 carry h for this wave's (row, j) ownership
    float carry[4][4];
    if (l15 < 8) {
#pragma unroll
        for (int og = 0; og < 4; ++og)
#pragma unroll
            for (int rg = 0; rg < 4; ++rg)
                carry[og][rg] = hidden[(size_t)(g * 64 + w * 16 + quad * 4 + rg) * HH
                                       + cp * 32 + og * 8 + l15];
    }

    int* cc = cnt + g * 128;

    for (int s = 0; s < 96; ++s) {
        const char* ab = (s & 1) ? aB1 : aB0;
        char* hout = (s & 1) ? hfrag0 : hfrag1;
        const char* bb = s ? bb1 : bb0;
        const bool dofc = fcblk && (s >= 1);

        f32x4 acc[8];
#pragma unroll
        for (int ct = 0; ct < 8; ++ct) {
            float bz = bv1[ct];
            if (s == 0) bz = bias0[cp * 128 + ct * 16 + l15];
            acc[ct] = (f32x4){bz, bz, bz, bz};
        }
        f32x4 fca = {0.f, 0.f, 0.f, 0.f};

        U128 A[16]; short8 Bt[16][8]; short8 Bf[16];
#pragma unroll
        for (int p = 0; p < 8; ++p) {
            A[p].u[0] = GLD64(ab + p * 1024);
            A[p].u[1] = GLD64(ab + p * 1024 + 8);
        }
#pragma unroll
        for (int p = 0; p < 3; ++p)
#pragma unroll
            for (int ct = 0; ct < 8; ++ct)
                Bt[p][ct] = *(const short8*)(bb + ct * 16384 + p * 1024);
        if (dofc) {
            Bf[0] = *(const short8*)(bf);
            Bf[1] = *(const short8*)(bf + 1024);
        }

#pragma unroll
        for (int it = 0; it < 16; ++it) {
            if (it + 8 < 16) {
                A[it + 8].u[0] = GLD64(ab + (it + 8) * 1024);
                A[it + 8].u[1] = GLD64(ab + (it + 8) * 1024 + 8);
            }
            if (it + 3 < 16) {
#pragma unroll
                for (int ct = 0; ct < 8; ++ct)
                    Bt[it + 3][ct] = *(const short8*)(bb + ct * 16384 + (it + 3) * 1024);
            }
            if (dofc && it + 2 < 16) Bf[it + 2] = *(const short8*)(bf + (it + 2) * 1024);
#pragma unroll
            for (int ct = 0; ct < 8; ++ct)
                acc[ct] = __builtin_amdgcn_mfma_f32_16x16x32_bf16(A[it].v, Bt[it][ct], acc[ct], 0, 0, 0);
            if (dofc) fca = __builtin_amdgcn_mfma_f32_16x16x32_bf16(A[it].v, Bf[it], fca, 0, 0, 0);
        }

        if (dofc) {
            const int ttt = 96 - s;
#pragma unroll
            for (int rg = 0; rg < 4; ++rg)
                out[(size_t)(g * 64 + w * 16 + quad * 4 + rg) * (TT * FF)
                    + ttt * FF + cp * 16 + l15] = fca[rg] + fcb;
        }

        // gate combine + h update; write h_new fragment-ordered into LDS
#pragma unroll
        for (int og = 0; og < 4; ++og)
#pragma unroll
            for (int rg = 0; rg < 4; ++rg) {
                float arz = acc[2 * og][rg], anh = acc[2 * og + 1][rg];
                float zsh = __shfl_xor(arz, 8, 64);
                float hsh = __shfl_xor(anh, 8, 64);
                if (l15 < 8) {
                    float r = sigmoidf_(arz);
                    float z = sigmoidf_(zsh);
                    float nv = tanhf_(anh + r * hsh);
                    float hn = (1.f - z) * nv + z * carry[og][rg];
                    carry[og][rg] = hn;
                    hfr[w * 512 + og * 128 + (quad * 4 + rg) * 8 + l15] = bf16bits(hn);
                }
            }
        __syncthreads();

        // coalesced fragment store of h_new (1 KB per row-frag tile)
        {
            int rfl = tid >> 6, l = tid & 63;
            const unsigned long long* src = (const unsigned long long*)&hfr[rfl * 512 + l * 8];
            size_t off = (size_t)((g * 4 + rfl) * 16 + cp) * 1024 + (size_t)l * 16;
            GST64(hout + off, src[0]);
            GST64(hout + off + 8, src[1]);
        }

        // row-group barrier (16 blocks): drain stores, relaxed add, spin
        asm volatile("s_waitcnt vmcnt(0)" ::: "memory");
        __syncthreads();
        if (tid == 0) {
            __hip_atomic_fetch_add(cc + s, 1, __ATOMIC_RELAXED, __HIP_MEMORY_SCOPE_AGENT);
            while (__hip_atomic_load(cc + s, __ATOMIC_RELAXED, __HIP_MEMORY_SCOPE_AGENT) < CPB)
                __builtin_amdgcn_s_sleep(1);
        }
        __syncthreads();
        asm volatile("" ::: "memory");
    }

    // final projection: h_96 (in hfrag0) -> out[:, 0, :]
    if (fcblk) {
        f32x4 fca = {0.f, 0.f, 0.f, 0.f};
        U128 A[16]; short8 Bf[16];
#pragma unroll
        for (int p = 0; p < 4; ++p) {
            A[p].u[0] = GLD64(aB0 + p * 1024);
            A[p].u[1] = GLD64(aB0 + p * 1024 + 8);
            Bf[p] = *(const short8*)(bf + p * 1024);
        }
#pragma unroll
        for (int it = 0; it < 16; ++it) {
            if (it + 4 < 16) {
                A[it + 4].u[0] = GLD64(aB0 + (it + 4) * 1024);
                A[it + 4].u[1] = GLD64(aB0 + (it + 4) * 1024 + 8);
                Bf[it + 4] = *(const short8*)(bf + (it + 4) * 1024);
            }
            fca = __builtin_amdgcn_mfma_f32_16x16x32_bf16(A[it].v, Bf[it], fca, 0, 0, 0);
        }
#pragma unroll
        for (int rg = 0; rg < 4; ++rg)
            out[(size_t)(g * 64 + w * 16 + quad * 4 + rg) * (TT * FF)
                + cp * 16 + l15] = fca[rg] + fcb;
    }
}

extern "C" void kernel_launch(void* const* d_in, const int* in_sizes, int n_in,
                              void* d_out, int out_size, void* d_ws, size_t ws_size,
                              hipStream_t stream) {
    const float* hidden = (const float*)d_in[0];
    const float* w_ih   = (const float*)d_in[1];
    const float* w_hh   = (const float*)d_in[2];
    const float* b_ih   = (const float*)d_in[3];
    const float* b_hh   = (const float*)d_in[4];
    const float* fc_w   = (const float*)d_in[5];
    const float* fc_b   = (const float*)d_in[6];
    float* out = (float*)d_out;

    char* ws = (char*)d_ws;
    size_t off = 0;
    auto alloc = [&](size_t bytes) -> void* {
        void* p = ws + off;
        off += (bytes + 255) & ~(size_t)255;
        return p;
    };
    char* Wg   = (char*)alloc((size_t)NGATE * HH * 2);
    char* W0g  = (char*)alloc((size_t)NGATE * HH * 2);
    char* Wfc  = (char*)alloc((size_t)FF * HH * 2);
    float* bias  = (float*)alloc(NGATE * 4);
    float* bias0 = (float*)alloc(NGATE * 4);
    char* hfrag0 = (char*)alloc((size_t)BB * HH * 2);
    char* hfrag1 = (char*)alloc((size_t)BB * HH * 2);
    int* cnt = (int*)alloc(GRP * 128 * 4);

    build_weights<<<NTOT, 256, 0, stream>>>(w_ih, w_hh, b_ih, b_hh, fc_w, fc_b,
                                            Wg, W0g, Wfc, bias, bias0);
    init_misc<<<(BB * HH / 8 + 255) / 256, 256, 0, stream>>>(hidden, hfrag0, cnt);
    gru_persist<<<512, 256, 0, stream>>>(Wg, W0g, Wfc, bias, bias0, fc_b, hidden,
                                         hfrag0, hfrag1, out, cnt);
}

// Round 5
// 1265.184 us; speedup vs baseline: 1.9290x; 1.9290x over previous
//
#include <hip/hip_runtime.h>
#include <hip/hip_bf16.h>

#define HH 512
#define FF 128
#define BB 2048
#define TT 96
#define NGATE 2048
#define NTOT 2176
#define GRP 16          // row groups (128 rows each) — XCD-local under id%8 dispatch
#define CPB 32          // col-part blocks per group

typedef short short8 __attribute__((ext_vector_type(8)));
typedef float f32x4 __attribute__((ext_vector_type(4)));

union U128 { unsigned long long u[2]; short8 v; };

__device__ __forceinline__ float sigmoidf_(float x) { return 1.f / (1.f + __expf(-x)); }
__device__ __forceinline__ float tanhf_(float x) {
    float e = __expf(-2.f * fabsf(x));
    float t = (1.f - e) / (1.f + e);
    return x < 0.f ? -t : t;
}

// byte offset of element (m, k) in fragment order: 16(m) x 32(k) tiles of 1 KB,
// lane = (m&15) + 16*((k>>3)&3) holds bytes [lane*16, lane*16+16).
__device__ __forceinline__ size_t frag_off(int m, int k, int K) {
    return (size_t)((m >> 4) * (K >> 5) + (k >> 5)) * 1024
         + (size_t)(((k >> 3) & 3) * 256 + (m & 15) * 16 + (k & 7) * 2);
}

__device__ __forceinline__ short bf16bits(float f) {
    __hip_bfloat16 b = __float2bfloat16(f);
    return *(short*)&b;
}

// Gate col layout (n < 2048): octet o=n>>5, gate=(n>>3)&3, j=o*8+(n&7):
// each aligned 32-col group = [r(8) z(8) i_n(8) h_n(8)] for 8 consecutive j.
// Weights in B-fragment order. n>=2048: fc_w row -> Wfc.
__global__ __launch_bounds__(256) void build_weights(
    const float* __restrict__ w_ih, const float* __restrict__ w_hh,
    const float* __restrict__ b_ih, const float* __restrict__ b_hh,
    const float* __restrict__ fc_w, const float* __restrict__ fc_b,
    char* __restrict__ Wg, char* __restrict__ W0g, char* __restrict__ Wfc,
    float* __restrict__ bias, float* __restrict__ bias0)
{
    const int n = blockIdx.x;
    const int tid = threadIdx.x;
    __shared__ float wih_s[FF];
    const bool is_out = (n >= NGATE);
    int gate = 3, gidx = 0, f = 0;
    if (is_out) {
        f = n - NGATE;
    } else {
        int o = n >> 5;
        gate = (n >> 3) & 3;
        int j = o * 8 + (n & 7);
        gidx = (gate == 0) ? j : (gate == 1) ? (512 + j) : (1024 + j);
    }
    if (!is_out && gate != 3 && tid < FF) wih_s[tid] = w_ih[gidx * FF + tid];
    __syncthreads();

    for (int k = tid; k < HH; k += 256) {
        float w, w0;
        if (is_out) {
            w = fc_w[f * HH + k];
            w0 = 0.f;
        } else if (gate == 3) {
            w = w_hh[gidx * HH + k];
            w0 = w;
        } else {
            float comb = 0.f;
#pragma unroll 8
            for (int ff2 = 0; ff2 < FF; ++ff2) comb += wih_s[ff2] * fc_w[ff2 * HH + k];
            if (gate == 2) { w = comb; w0 = 0.f; }
            else { float whh = w_hh[gidx * HH + k]; w = whh + comb; w0 = whh; }
        }
        if (is_out) {
            *(short*)(Wfc + frag_off(f, k, HH)) = bf16bits(w);
        } else {
            *(short*)(Wg  + frag_off(n, k, HH)) = bf16bits(w);
            *(short*)(W0g + frag_off(n, k, HH)) = bf16bits(w0);
        }
    }
    if (tid == 0 && !is_out) {
        float b, b0;
        float cb = 0.f;
        if (gate != 3)
            for (int ff2 = 0; ff2 < FF; ++ff2) cb += fc_b[ff2] * w_ih[gidx * FF + ff2];
        if (gate <= 1)      { float s2 = b_ih[gidx] + b_hh[gidx]; b = s2 + cb; b0 = s2; }
        else if (gate == 2) { b = b_ih[gidx] + cb; b0 = b_ih[gidx]; }
        else                { b = b_hh[gidx]; b0 = b_hh[gidx]; }
        bias[n] = b; bias0[n] = b0;
    }
}

// hidden (fp32 row-major) -> h_0 bf16 in fragment order; zero sync counters.
__global__ __launch_bounds__(256) void init_misc(
    const float* __restrict__ hidden, char* __restrict__ hfrag, int* __restrict__ cnt)
{
    int i = blockIdx.x * 256 + threadIdx.x;  // 131072 granules of 8 k-elements
    int row = i >> 6, k0 = (i & 63) << 3;
    short8 v;
#pragma unroll
    for (int t = 0; t < 8; ++t) v[t] = bf16bits(hidden[(size_t)row * HH + k0 + t]);
    *(short8*)(hfrag + frag_off(row, k0, HH)) = v;
    if (i < GRP * 128) cnt[i] = 0;
}

#define GLD64(p) __hip_atomic_load((const unsigned long long*)(p), __ATOMIC_RELAXED, __HIP_MEMORY_SCOPE_AGENT)
#define GST64(p, v) __hip_atomic_store((unsigned long long*)(p), (v), __ATOMIC_RELAXED, __HIP_MEMORY_SCOPE_AGENT)

// Persistent GRU. 512 blocks = 16 row-groups(128 rows) x 32 col-parts(64 gate cols),
// 2 blocks/CU (LDS 68 KB). Wave = 32 rows (2 row-frags) x 64 cols (4 col-frags),
// acc[2][4]. B (weights): staged ONCE into LDS, conflict-free ds_read_b128 all 96
// steps. A (h): L2-hot relaxed agent atomics, depth-6 register window (no spill:
// ~180 VGPR total). fc projection fused into gate K-loop on wave (c>>3), reusing
// the A registers. Fence-free group barrier (r3-proven).
__global__ __launch_bounds__(256, 2) void gru_persist(
    const char* __restrict__ Wg, const char* __restrict__ W0g, const char* __restrict__ Wfc,
    const float* __restrict__ bias, const float* __restrict__ bias0,
    const float* __restrict__ fc_b, const float* __restrict__ hidden,
    char* __restrict__ hfrag0, char* __restrict__ hfrag1,
    float* __restrict__ out, int* __restrict__ cnt)
{
    __shared__ __align__(16) short Bs[32768];   // 64 KB: [ct(4)][chunk(16)][lane*8]
    __shared__ __align__(16) short hfr[2048];   // 4 KB packed h_new

    const int tid = threadIdx.x;
    const int lane = tid & 63, w = tid >> 6;
    const int l15 = lane & 15, quad = lane >> 4;
    const int g = blockIdx.x & 15, c = blockIdx.x >> 4;   // group on XCD (g&7)

    const char* aB0 = hfrag0 + (size_t)(g * 8 + w * 2) * 16384 + lane * 16;
    const char* aB1 = hfrag1 + (size_t)(g * 8 + w * 2) * 16384 + lane * 16;
    const char* bf  = Wfc + (size_t)(c & 7) * 16384 + lane * 16;
    const bool fcw = (w == (c >> 3));          // this wave also does the fc tile

    float bv[4];
#pragma unroll
    for (int ct = 0; ct < 4; ++ct) bv[ct] = bias[c * 64 + ct * 16 + l15];
    const float fcb = fc_b[(c & 7) * 16 + l15];

    // fp32 carry h for this wave's (row, j) ownership (j = c*16 + og*8 + l15, l15<8)
    float carry[2][2][4];
    if (l15 < 8) {
#pragma unroll
        for (int rt = 0; rt < 2; ++rt)
#pragma unroll
            for (int og = 0; og < 2; ++og)
#pragma unroll
                for (int rg = 0; rg < 4; ++rg)
                    carry[rt][og][rg] =
                        hidden[(size_t)(g * 128 + w * 32 + rt * 16 + quad * 4 + rg) * HH
                               + c * 16 + og * 8 + l15];
    }

    int* cc = cnt + g * 128;

    // ---- stage this block's 64 gate cols of Wg into LDS (once) ----
    {
        const char* wsrc = Wg + (size_t)c * 65536;
#pragma unroll
        for (int i = 0; i < 16; ++i) {
            int idx = i * 256 + tid;
            *(int4*)((char*)Bs + idx * 16) = *(const int4*)(wsrc + (size_t)idx * 16);
        }
    }
    __syncthreads();

    // shared epilogue: gates -> carry -> hfr pack -> frag store -> group barrier
    auto epilogue = [&](f32x4 (&acc)[2][4], int s, char* hout) {
#pragma unroll
        for (int rt = 0; rt < 2; ++rt)
#pragma unroll
            for (int og = 0; og < 2; ++og)
#pragma unroll
                for (int rg = 0; rg < 4; ++rg) {
                    float arz = acc[rt][2 * og][rg], anh = acc[rt][2 * og + 1][rg];
                    float zsh = __shfl_xor(arz, 8, 64);
                    float hsh = __shfl_xor(anh, 8, 64);
                    if (l15 < 8) {
                        float r = sigmoidf_(arz);
                        float z = sigmoidf_(zsh);
                        float nv = tanhf_(anh + r * hsh);
                        float hn = (1.f - z) * nv + z * carry[rt][og][rg];
                        carry[rt][og][rg] = hn;
                        hfr[(w * 32 + rt * 16 + quad * 4 + rg) * 16 + og * 8 + l15] = bf16bits(hn);
                    }
                }
        __syncthreads();
        {
            int lrow = tid >> 1, half = tid & 1;
            const unsigned long long* src = (const unsigned long long*)&hfr[lrow * 16 + half * 8];
            size_t off = (size_t)((g * 8 + (lrow >> 4)) * 16 + (c >> 1)) * 1024
                       + (size_t)((((c << 1) + half) & 3) * 256 + (lrow & 15) * 16);
            GST64(hout + off, src[0]);
            GST64(hout + off + 8, src[1]);
        }
        asm volatile("s_waitcnt vmcnt(0)" ::: "memory");
        __syncthreads();
        if (tid == 0) {
            __hip_atomic_fetch_add(cc + s, 1, __ATOMIC_RELAXED, __HIP_MEMORY_SCOPE_AGENT);
            while (__hip_atomic_load(cc + s, __ATOMIC_RELAXED, __HIP_MEMORY_SCOPE_AGENT) < CPB)
                __builtin_amdgcn_s_sleep(1);
        }
        __syncthreads();
        asm volatile("" ::: "memory");
    };

    // ---- step 0: x=0 weights streamed from global (one step, amortized) ----
    {
        f32x4 acc[2][4];
#pragma unroll
        for (int ct = 0; ct < 4; ++ct) {
            float b0 = bias0[c * 64 + ct * 16 + l15];
            acc[0][ct] = (f32x4){b0, b0, b0, b0};
            acc[1][ct] = acc[0][ct];
        }
        const char* bb0 = W0g + (size_t)c * 65536 + lane * 16;
        U128 A[2][2]; short8 Bt[2][4];
#pragma unroll
        for (int p = 0; p < 2; ++p) {
#pragma unroll
            for (int rt = 0; rt < 2; ++rt) {
                A[p][rt].u[0] = GLD64(aB0 + rt * 16384 + p * 1024);
                A[p][rt].u[1] = GLD64(aB0 + rt * 16384 + p * 1024 + 8);
            }
#pragma unroll
            for (int ct = 0; ct < 4; ++ct)
                Bt[p][ct] = *(const short8*)(bb0 + ct * 16384 + p * 1024);
        }
#pragma unroll
        for (int it = 0; it < 16; ++it) {
            const int sl = it & 1;
#pragma unroll
            for (int rt = 0; rt < 2; ++rt)
#pragma unroll
                for (int ct = 0; ct < 4; ++ct)
                    acc[rt][ct] = __builtin_amdgcn_mfma_f32_16x16x32_bf16(A[sl][rt].v, Bt[sl][ct], acc[rt][ct], 0, 0, 0);
            if (it + 2 < 16) {
#pragma unroll
                for (int rt = 0; rt < 2; ++rt) {
                    A[sl][rt].u[0] = GLD64(aB0 + rt * 16384 + (it + 2) * 1024);
                    A[sl][rt].u[1] = GLD64(aB0 + rt * 16384 + (it + 2) * 1024 + 8);
                }
#pragma unroll
                for (int ct = 0; ct < 4; ++ct)
                    Bt[sl][ct] = *(const short8*)(bb0 + ct * 16384 + (it + 2) * 1024);
            }
        }
        epilogue(acc, 0, hfrag1);
    }

    // ---- steps 1..95: B from LDS, A depth-6 window, fc fused ----
    for (int s = 1; s < 96; ++s) {
        const char* ab = (s & 1) ? aB1 : aB0;
        char* hout = (s & 1) ? hfrag0 : hfrag1;
        const int tt = 96 - s;

        f32x4 acc[2][4];
#pragma unroll
        for (int ct = 0; ct < 4; ++ct) {
            acc[0][ct] = (f32x4){bv[ct], bv[ct], bv[ct], bv[ct]};
            acc[1][ct] = acc[0][ct];
        }
        f32x4 fca[2] = {{0.f,0.f,0.f,0.f},{0.f,0.f,0.f,0.f}};

        U128 A[6][2]; short8 Bt[2][4]; short8 Bf[4];
#pragma unroll
        for (int p = 0; p < 6; ++p)
#pragma unroll
            for (int rt = 0; rt < 2; ++rt) {
                A[p][rt].u[0] = GLD64(ab + rt * 16384 + p * 1024);
                A[p][rt].u[1] = GLD64(ab + rt * 16384 + p * 1024 + 8);
            }
#pragma unroll
        for (int p = 0; p < 2; ++p)
#pragma unroll
            for (int ct = 0; ct < 4; ++ct)
                Bt[p][ct] = *(const short8*)((const char*)Bs + ct * 16384 + p * 1024 + lane * 16);
        if (fcw) {
#pragma unroll
            for (int p = 0; p < 4; ++p)
                Bf[p] = *(const short8*)(bf + p * 1024);
        }

#pragma unroll
        for (int it = 0; it < 16; ++it) {
            const int sa = it % 6, sb = it & 1, sf = it & 3;
#pragma unroll
            for (int rt = 0; rt < 2; ++rt)
#pragma unroll
                for (int ct = 0; ct < 4; ++ct)
                    acc[rt][ct] = __builtin_amdgcn_mfma_f32_16x16x32_bf16(A[sa][rt].v, Bt[sb][ct], acc[rt][ct], 0, 0, 0);
            if (fcw) {
                fca[0] = __builtin_amdgcn_mfma_f32_16x16x32_bf16(A[sa][0].v, Bf[sf], fca[0], 0, 0, 0);
                fca[1] = __builtin_amdgcn_mfma_f32_16x16x32_bf16(A[sa][1].v, Bf[sf], fca[1], 0, 0, 0);
            }
            if (it + 6 < 16) {
#pragma unroll
                for (int rt = 0; rt < 2; ++rt) {
                    A[sa][rt].u[0] = GLD64(ab + rt * 16384 + (it + 6) * 1024);
                    A[sa][rt].u[1] = GLD64(ab + rt * 16384 + (it + 6) * 1024 + 8);
                }
            }
            if (it + 2 < 16) {
#pragma unroll
                for (int ct = 0; ct < 4; ++ct)
                    Bt[sb][ct] = *(const short8*)((const char*)Bs + ct * 16384 + (it + 2) * 1024 + lane * 16);
            }
            if (fcw && it + 4 < 16) Bf[sf] = *(const short8*)(bf + (it + 4) * 1024);
        }

        if (fcw) {
#pragma unroll
            for (int rt = 0; rt < 2; ++rt)
#pragma unroll
                for (int rg = 0; rg < 4; ++rg)
                    out[(size_t)(g * 128 + w * 32 + rt * 16 + quad * 4 + rg) * (TT * FF)
                        + tt * FF + (c & 7) * 16 + l15] = fca[rt][rg] + fcb;
        }

        epilogue(acc, s, hout);
    }

    // ---- final projection: h_96 (hfrag0) -> out[:, 0, :] ----
    if (fcw) {
        f32x4 fca[2] = {{0.f,0.f,0.f,0.f},{0.f,0.f,0.f,0.f}};
        U128 A[4][2]; short8 Bf[4];
#pragma unroll
        for (int p = 0; p < 4; ++p) {
#pragma unroll
            for (int rt = 0; rt < 2; ++rt) {
                A[p][rt].u[0] = GLD64(aB0 + rt * 16384 + p * 1024);
                A[p][rt].u[1] = GLD64(aB0 + rt * 16384 + p * 1024 + 8);
            }
            Bf[p] = *(const short8*)(bf + p * 1024);
        }
#pragma unroll
        for (int it = 0; it < 16; ++it) {
            const int sl = it & 3;
            fca[0] = __builtin_amdgcn_mfma_f32_16x16x32_bf16(A[sl][0].v, Bf[sl], fca[0], 0, 0, 0);
            fca[1] = __builtin_amdgcn_mfma_f32_16x16x32_bf16(A[sl][1].v, Bf[sl], fca[1], 0, 0, 0);
            if (it + 4 < 16) {
#pragma unroll
                for (int rt = 0; rt < 2; ++rt) {
                    A[sl][rt].u[0] = GLD64(aB0 + rt * 16384 + (it + 4) * 1024);
                    A[sl][rt].u[1] = GLD64(aB0 + rt * 16384 + (it + 4) * 1024 + 8);
                }
                Bf[sl] = *(const short8*)(bf + (it + 4) * 1024);
            }
        }
#pragma unroll
        for (int rt = 0; rt < 2; ++rt)
#pragma unroll
            for (int rg = 0; rg < 4; ++rg)
                out[(size_t)(g * 128 + w * 32 + rt * 16 + quad * 4 + rg) * (TT * FF)
                    + (c & 7) * 16 + l15] = fca[rt][rg] + fcb;
    }
}

extern "C" void kernel_launch(void* const* d_in, const int* in_sizes, int n_in,
                              void* d_out, int out_size, void* d_ws, size_t ws_size,
                              hipStream_t stream) {
    const float* hidden = (const float*)d_in[0];
    const float* w_ih   = (const float*)d_in[1];
    const float* w_hh   = (const float*)d_in[2];
    const float* b_ih   = (const float*)d_in[3];
    const float* b_hh   = (const float*)d_in[4];
    const float* fc_w   = (const float*)d_in[5];
    const float* fc_b   = (const float*)d_in[6];
    float* out = (float*)d_out;

    char* ws = (char*)d_ws;
    size_t off = 0;
    auto alloc = [&](size_t bytes) -> void* {
        void* p = ws + off;
        off += (bytes + 255) & ~(size_t)255;
        return p;
    };
    char* Wg   = (char*)alloc((size_t)NGATE * HH * 2);
    char* W0g  = (char*)alloc((size_t)NGATE * HH * 2);
    char* Wfc  = (char*)alloc((size_t)FF * HH * 2);
    float* bias  = (float*)alloc(NGATE * 4);
    float* bias0 = (float*)alloc(NGATE * 4);
    char* hfrag0 = (char*)alloc((size_t)BB * HH * 2);
    char* hfrag1 = (char*)alloc((size_t)BB * HH * 2);
    int* cnt = (int*)alloc(GRP * 128 * 4);

    build_weights<<<NTOT, 256, 0, stream>>>(w_ih, w_hh, b_ih, b_hh, fc_w, fc_b,
                                            Wg, W0g, Wfc, bias, bias0);
    init_misc<<<(BB * HH / 8 + 255) / 256, 256, 0, stream>>>(hidden, hfrag0, cnt);
    gru_persist<<<512, 256, 0, stream>>>(Wg, W0g, Wfc, bias, bias0, fc_b, hidden,
                                         hfrag0, hfrag1, out, cnt);
}